// Round 2
// baseline (324.782 us; speedup 1.0000x reference)
//
#include <hip/hip_runtime.h>

#define T_STEPS 4096
#define BLOCK   1024
#define CHUNK   4

constexpr float CAP     = 13.5f;
constexpr float MAXR    = 5.0f;
constexpr float S0      = 6.75f;
constexpr float DT      = (float)(5.0 / 60.0);   // KW_TO_KWH rounded to fp32, same as jax
constexpr float FIVE_DT = 5.0f * DT;
constexpr float BIG     = 3.402823466e+38f;

struct Trip { float d, l, h; };  // s -> clip(s + d, l, h)

// apply p first, then q
__device__ __forceinline__ Trip combine(const Trip& p, const Trip& q) {
    Trip r;
    r.d = p.d + q.d;
    r.l = fminf(fmaxf(p.l + q.d, q.l), q.h);
    r.h = fminf(fmaxf(p.h + q.d, q.l), q.h);
    return r;
}

__global__ __launch_bounds__(BLOCK) void battery_kernel(
    const float* __restrict__ ga, const float* __restrict__ pa,
    const float* __restrict__ pp, const float* __restrict__ pr,
    float* __restrict__ trace, float* __restrict__ cost)
{
    const int b    = blockIdx.x;
    const int tid  = threadIdx.x;
    const int lane = tid & 63;
    const int w    = tid >> 6;            // wave id, 0..15
    const long long rowOff = (long long)b * T_STEPS;
    const int t0   = tid * CHUNK;

    // perfectly coalesced float4 loads (lane i -> 16B at i*16)
    const float4 g4  = *reinterpret_cast<const float4*>(ga + rowOff + t0);
    const float4 pa4 = *reinterpret_cast<const float4*>(pa + rowOff + t0);
    const float4 pp4 = *reinterpret_cast<const float4*>(pp + rowOff + t0);
    const float4 pr4 = *reinterpret_cast<const float4*>(pr + rowOff + t0);
    const float gaA[4] = {g4.x,  g4.y,  g4.z,  g4.w};
    const float paA[4] = {pa4.x, pa4.y, pa4.z, pa4.w};
    const float ppA[4] = {pp4.x, pp4.y, pp4.z, pp4.w};
    const float prA[4] = {pr4.x, pr4.y, pr4.z, pr4.w};

    // ---- phase 1: local composition of this thread's 4 steps ----
    Trip acc;
    #pragma unroll
    for (int j = 0; j < CHUNK; ++j) {
        float rate = fminf(fmaxf(paA[j] * ppA[j], 0.0f), MAXR);
        float a    = rate * DT;                       // prov_pv_amount
        float u    = (gaA[j] * MAXR) * DT;            // attempted grid amount
        float d    = a + fminf(fmaxf(u, -FIVE_DT), FIVE_DT - a);
        float h    = fminf(fmaxf(CAP + u, CAP - FIVE_DT), CAP);
        Trip f = {d, 0.0f, h};
        acc = (j == 0) ? f : combine(acc, f);
    }

    // ---- wave-level inclusive scan (64 lanes) ----
    #pragma unroll
    for (int off = 1; off < 64; off <<= 1) {
        Trip p;
        p.d = __shfl_up(acc.d, off);
        p.l = __shfl_up(acc.l, off);
        p.h = __shfl_up(acc.h, off);
        if (lane >= off) acc = combine(p, acc);
    }

    __shared__ float aggD[16], aggL[16], aggH[16];
    if (lane == 63) { aggD[w] = acc.d; aggL[w] = acc.l; aggH[w] = acc.h; }

    // exclusive-within-wave triple
    Trip ex;
    ex.d = __shfl_up(acc.d, 1);
    ex.l = __shfl_up(acc.l, 1);
    ex.h = __shfl_up(acc.h, 1);
    if (lane == 0) { ex.d = 0.0f; ex.l = -BIG; ex.h = BIG; }

    __syncthreads();

    // prefix over earlier waves (uniform within a wave, <=15 iters)
    Trip pre = {0.0f, -BIG, BIG};
    for (int i = 0; i < w; ++i) {
        Trip q = {aggD[i], aggL[i], aggH[i]};
        pre = combine(pre, q);
    }
    Trip tot = combine(pre, ex);
    float s = fminf(fmaxf(S0 + tot.d, tot.l), tot.h);  // state entering this chunk

    // ---- phase 2: replay 4 steps with faithful reference arithmetic ----
    float st[CHUNK], ct[CHUNK];
    #pragma unroll
    for (int j = 0; j < CHUNK; ++j) {
        float rate      = fminf(fmaxf(paA[j] * ppA[j], 0.0f), MAXR);
        float ppc       = rate * DT;
        float after_pv  = fminf(fmaxf(s + ppc, 0.0f), CAP);
        float realised  = after_pv - s;               // realised_pv_amt
        float apr       = realised / DT;              // actual_pv_rate
        float pv_export = realised - ppA[j] * DT;
        float agr       = gaA[j] * MAXR;
        float rgr       = fminf(fmaxf(agr, -MAXR), MAXR - apr);
        float ns        = fminf(fmaxf(after_pv + rgr * DT, 0.0f), CAP);
        float grid_amt  = ns - after_pv;
        st[j] = ns;
        ct[j] = (prA[j] / 1000.0f) * (grid_amt + pv_export);
        s = ns;
    }

    // cost: [B, T], row base 16B-aligned -> direct coalesced float4 store
    float4 c4; c4.x = ct[0]; c4.y = ct[1]; c4.z = ct[2]; c4.w = ct[3];
    *reinterpret_cast<float4*>(cost + rowOff + t0) = c4;

    // trace: [B, T+1], +1 offset breaks alignment -> stage via LDS, store coalesced
    __shared__ float tr[T_STEPS];
    float4 s4; s4.x = st[0]; s4.y = st[1]; s4.z = st[2]; s4.w = st[3];
    *reinterpret_cast<float4*>(tr + t0) = s4;         // ds_write_b128, conflict-free
    __syncthreads();

    const long long trBase = (long long)b * (T_STEPS + 1);
    if (tid == 0) trace[trBase] = S0;
    #pragma unroll
    for (int k = 0; k < CHUNK; ++k) {
        int i = tid + k * BLOCK;                      // coalesced scalar stores
        trace[trBase + 1 + i] = tr[i];
    }
}

extern "C" void kernel_launch(void* const* d_in, const int* in_sizes, int n_in,
                              void* d_out, int out_size, void* d_ws, size_t ws_size,
                              hipStream_t stream) {
    const float* ga = (const float*)d_in[0];   // grid_action
    const float* pa = (const float*)d_in[1];   // pv_action
    const float* pp = (const float*)d_in[2];   // pv_power
    const float* pr = (const float*)d_in[3];   // price
    const int B = in_sizes[0] / T_STEPS;
    float* trace = (float*)d_out;
    float* cost  = (float*)d_out + (long long)B * (T_STEPS + 1);
    battery_kernel<<<B, BLOCK, 0, stream>>>(ga, pa, pp, pr, trace, cost);
}